// Round 1
// baseline (71.139 us; speedup 1.0000x reference)
//
#include <hip/hip_runtime.h>

// VA forward: out[row, 3j:3j+3] = M(theta_row) @ ((p + t) * (p != 0))
// where M = Rz(th2) * Ry(th0) * Rx(th1), t = th[3:6].
// One thread per joint (3 floats). Memory-bound; trig redundant per thread
// (25x per row) but theta loads broadcast within-wave from L1.

constexpr int JOINTS = 25;

__global__ __launch_bounds__(256) void va_kernel(
    const float* __restrict__ conv,
    const float* __restrict__ theta,
    float* __restrict__ out,
    int total)   // total = N * JOINTS joint-tasks
{
    int idx = blockIdx.x * 256 + threadIdx.x;
    if (idx >= total) return;

    unsigned row = (unsigned)idx / JOINTS;        // magic-mul div by 25
    unsigned j   = (unsigned)idx - row * JOINTS;

    const float* th = theta + (size_t)row * 6;
    float ay = th[0], ax = th[1], az = th[2];
    float tx = th[3], ty = th[4], tz = th[5];

    float sy = __sinf(ay), cy = __cosf(ay);
    float sx = __sinf(ax), cx = __cosf(ax);
    float sz = __sinf(az), cz = __cosf(az);

    // M = Rz(az) * Ry(ay) * Rx(ax)
    float m00 = cz * cy;
    float m01 = -sz * cx + cz * sy * sx;
    float m02 =  sz * sx + cz * sy * cx;
    float m10 = sz * cy;
    float m11 =  cz * cx + sz * sy * sx;
    float m12 = -cz * sx + sz * sy * cx;
    float m20 = -sy;
    float m21 = cy * sx;
    float m22 = cy * cx;

    const float* p = conv + (size_t)row * 75 + j * 3;
    float x = p[0], y = p[1], z = p[2];

    float qx = (x != 0.0f) ? (x + tx) : 0.0f;
    float qy = (y != 0.0f) ? (y + ty) : 0.0f;
    float qz = (z != 0.0f) ? (z + tz) : 0.0f;

    float ox = m00 * qx + m01 * qy + m02 * qz;
    float oy = m10 * qx + m11 * qy + m12 * qz;
    float oz = m20 * qx + m21 * qy + m22 * qz;

    float* o = out + (size_t)row * 75 + j * 3;
    o[0] = ox;
    o[1] = oy;
    o[2] = oz;
}

extern "C" void kernel_launch(void* const* d_in, const int* in_sizes, int n_in,
                              void* d_out, int out_size, void* d_ws, size_t ws_size,
                              hipStream_t stream) {
    const float* conv  = (const float*)d_in[0];
    const float* theta = (const float*)d_in[1];
    float* out = (float*)d_out;

    int total = out_size / 3;                 // N * 25 joint tasks
    int blocks = (total + 255) / 256;
    va_kernel<<<blocks, 256, 0, stream>>>(conv, theta, out, total);
}